// Round 6
// baseline (411.819 us; speedup 1.0000x reference)
//
#include <hip/hip_runtime.h>
#include <hip/hip_cooperative_groups.h>
#include <stdint.h>

namespace cg = cooperative_groups;

typedef __bf16 bf16x8 __attribute__((ext_vector_type(8)));
typedef float f32x4 __attribute__((ext_vector_type(4)));

#define EPS 1e-5f

#define WAITVM(N) asm volatile("s_waitcnt vmcnt(" #N ")" ::: "memory")
#define WAITLGKM0 asm volatile("s_waitcnt lgkmcnt(0)" ::: "memory")

__device__ __forceinline__ void gl16(const void* g, void* l) {
    __builtin_amdgcn_global_load_lds(
        (const __attribute__((address_space(1))) unsigned int*)g,
        (__attribute__((address_space(3))) unsigned int*)l, 16, 0, 0);
}

__device__ __forceinline__ float b2f(unsigned short u) {
    union { unsigned int i; float f; } c; c.i = ((unsigned int)u) << 16; return c.f;
}
__device__ __forceinline__ unsigned short f2b(float f) {
    union { float f; unsigned int i; } c; c.f = f;
    unsigned int i = c.i;
    return (unsigned short)((i + 0x7FFFu + ((i >> 16) & 1u)) >> 16);
}

// Fused pre-chain: stats + params + zero (S1) | ctx (S2) | w2 (S3).
// Cooperative launch, grid 512 x 256 thr, 2 blocks/CU guaranteed
// (static LDS ~23 KB, __launch_bounds__(256,2)).
// All stage bodies are verbatim ports of the r5-passing kernels.
__global__ __launch_bounds__(256, 2) void k_attn(
    const float* __restrict__ x2,
    const float* __restrict__ lw, const float* __restrict__ rw,
    const float* __restrict__ lb, const float* __restrict__ g1,
    const float* __restrict__ b1, const float* __restrict__ rb,
    const float* __restrict__ ga, const float* __restrict__ ba,
    unsigned short* __restrict__ wt1, unsigned short* __restrict__ rwb,
    unsigned short* __restrict__ vec, float2* __restrict__ stats,
    float* __restrict__ ctxr, unsigned short* __restrict__ w2t) {
    __shared__ float E[64 * 36];
    __shared__ float Q[64 * 36];
    __shared__ float gs[32], bs[32];
    __shared__ float ctx_s[1024];
    __shared__ float cinv[32];
    cg::grid_group grid = cg::this_grid();
    const int bid = blockIdx.x;
    const int t = threadIdx.x;
    const int lane = t & 63, w = t >> 6;

    // ---- S1a: per-row LN stats of x2; 64 rows per block ----
#pragma unroll 4
    for (int it = 0; it < 16; ++it) {
        size_t row = (size_t)bid * 64 + it * 4 + w;
        float4 f = *(const float4*)(x2 + row * 256 + lane * 4);
        float s = f.x + f.y + f.z + f.w;
        float q = f.x * f.x + f.y * f.y + f.z * f.z + f.w * f.w;
#pragma unroll
        for (int msk = 1; msk < 64; msk <<= 1) {
            s += __shfl_xor(s, msk, 64);
            q += __shfl_xor(q, msk, 64);
        }
        float mn = s * (1.0f / 256.0f);
        float rstd = rsqrtf(q * (1.0f / 256.0f) - mn * mn + EPS);
        if (lane == 0) stats[row] = make_float2(mn, rstd);
    }

    // ---- S1b: params canonicalization + ctxr zero (grid-stride) ----
    // wt1: [kb(64)][n(256)][8], B[n][k]=lw[k][n]; rwb plain [512][256];
    // vec = {lb, g1, b1, rb, ga, ba}; tail zeroes ctxr[65536].
    for (int gid = bid * 256 + t; gid < 329984; gid += 131072) {
        if (gid < 131072) {
            int k = gid >> 8, n = gid & 255;
            wt1[((size_t)(k >> 3) * 256 + n) * 8 + (k & 7)] = f2b(lw[gid]);
        } else if (gid < 262144) {
            int j = gid - 131072;
            rwb[j] = f2b(rw[j]);
        } else if (gid < 264448) {
            int j = gid - 262144;
            if (j < 256)       vec[j] = f2b(lb[j]);
            else if (j < 512)  vec[j] = f2b(g1[j - 256]);
            else if (j < 768)  vec[j] = f2b(b1[j - 512]);
            else if (j < 1280) vec[j] = f2b(rb[j - 768]);
            else if (j < 1792) vec[j] = f2b(ga[j - 1280]);
            else               vec[j] = f2b(ba[j - 1792]);
        } else {
            ctxr[gid - 264448] = 0.0f;
        }
    }
    __threadfence();
    grid.sync();

    // ---- S2: ctxraw[b,h,d,e] += sum_m q[d,m]*E[e,m] (r2-proven body) ----
    {
        int bh = bid >> 3;
        int b = bh >> 3, h = bh & 7;
        int ch = bid & 7;
        if (t < 32) { gs[t] = b2f(vec[256 + h * 32 + t]); bs[t] = b2f(vec[512 + h * 32 + t]); }
        __syncthreads();
        int d = t >> 3, e0 = (t & 7) * 4;
        float a0 = 0.f, a1 = 0.f, a2 = 0.f, a3 = 0.f;
        const float* base = x2 + ((size_t)b * 4096 + ch * 512) * 256 + h * 32;
        int srow = b * 4096 + ch * 512;
        const int m = t >> 2, c0 = (t & 3) * 8;
        for (int s0 = 0; s0 < 512; s0 += 64) {
            float2 st = stats[srow + s0 + m];
            const float4* p = (const float4*)(base + (size_t)(s0 + m) * 256 + c0);
            float4 f0 = p[0], f1 = p[1];
            float ev[8];
            ev[0] = __expf((f0.x - st.x) * st.y * gs[c0 + 0] + bs[c0 + 0]);
            ev[1] = __expf((f0.y - st.x) * st.y * gs[c0 + 1] + bs[c0 + 1]);
            ev[2] = __expf((f0.z - st.x) * st.y * gs[c0 + 2] + bs[c0 + 2]);
            ev[3] = __expf((f0.w - st.x) * st.y * gs[c0 + 3] + bs[c0 + 3]);
            ev[4] = __expf((f1.x - st.x) * st.y * gs[c0 + 4] + bs[c0 + 4]);
            ev[5] = __expf((f1.y - st.x) * st.y * gs[c0 + 5] + bs[c0 + 5]);
            ev[6] = __expf((f1.z - st.x) * st.y * gs[c0 + 6] + bs[c0 + 6]);
            ev[7] = __expf((f1.w - st.x) * st.y * gs[c0 + 7] + bs[c0 + 7]);
            float ps = ev[0] + ev[1] + ev[2] + ev[3] + ev[4] + ev[5] + ev[6] + ev[7];
            ps += __shfl_xor(ps, 1, 64);
            ps += __shfl_xor(ps, 2, 64);
            float qi = 1.0f / ps;
            *(float4*)(E + m * 36 + c0)     = make_float4(ev[0], ev[1], ev[2], ev[3]);
            *(float4*)(E + m * 36 + c0 + 4) = make_float4(ev[4], ev[5], ev[6], ev[7]);
            *(float4*)(Q + m * 36 + c0)     = make_float4(ev[0]*qi, ev[1]*qi, ev[2]*qi, ev[3]*qi);
            *(float4*)(Q + m * 36 + c0 + 4) = make_float4(ev[4]*qi, ev[5]*qi, ev[6]*qi, ev[7]*qi);
            __syncthreads();
#pragma unroll 4
            for (int mm = 0; mm < 64; mm++) {
                float qd = Q[mm * 36 + d];
                float4 e4 = *(const float4*)(E + mm * 36 + e0);
                a0 += qd * e4.x; a1 += qd * e4.y; a2 += qd * e4.z; a3 += qd * e4.w;
            }
            __syncthreads();
        }
        float* dst = ctxr + ((size_t)bh << 10) + (d << 5) + e0;
        atomicAdd(dst + 0, a0);
        atomicAdd(dst + 1, a1);
        atomicAdd(dst + 2, a2);
        atomicAdd(dst + 3, a3);
    }
    __threadfence();
    grid.sync();

    // ---- S3: w2t[b][kb][o][8] = (1/colsum[c]) * sum_d ctx[d,c]*rw[o,h*32+d] ----
    {
        int blk = bid;
        int b = blk >> 6, h = (blk >> 3) & 7, os = blk & 7;
        int bh = b * 8 + h;
#pragma unroll
        for (int i = 0; i < 4; i++) ctx_s[t + 256 * i] = ctxr[((size_t)bh << 10) + t + 256 * i];
        __syncthreads();
        if (t < 32) {
            float s = 0.f;
#pragma unroll
            for (int d = 0; d < 32; d++) s += ctx_s[d * 32 + t];
            cinv[t] = 1.0f / s;
        }
        __syncthreads();
        int o = os * 64 + (t >> 2);
        int e0 = (t & 3) * 8;
        float wv[32];
        const uint4* wp = (const uint4*)(rwb + (size_t)o * 256 + h * 32);
#pragma unroll
        for (int qd = 0; qd < 4; qd++) {
            uint4 u = wp[qd];
            unsigned int uu[4] = {u.x, u.y, u.z, u.w};
#pragma unroll
            for (int j = 0; j < 4; j++) {
                wv[qd * 8 + j * 2]     = b2f((unsigned short)(uu[j] & 0xFFFFu));
                wv[qd * 8 + j * 2 + 1] = b2f((unsigned short)(uu[j] >> 16));
            }
        }
        float s[8];
#pragma unroll
        for (int j = 0; j < 8; j++) s[j] = 0.f;
#pragma unroll 8
        for (int d = 0; d < 32; d++) {
            float wd = wv[d];
#pragma unroll
            for (int j = 0; j < 8; j++) s[j] += ctx_s[d * 32 + e0 + j] * wd;
        }
        ushort4 o4a, o4b;
        o4a.x = f2b(s[0] * cinv[e0 + 0]); o4a.y = f2b(s[1] * cinv[e0 + 1]);
        o4a.z = f2b(s[2] * cinv[e0 + 2]); o4a.w = f2b(s[3] * cinv[e0 + 3]);
        o4b.x = f2b(s[4] * cinv[e0 + 4]); o4b.y = f2b(s[5] * cinv[e0 + 5]);
        o4b.z = f2b(s[6] * cinv[e0 + 6]); o4b.w = f2b(s[7] * cinv[e0 + 7]);
        int kb = h * 4 + (e0 >> 3);
        unsigned short* dst = w2t + (size_t)b * 131072 + ((size_t)kb * 512 + o) * 8;
        *(ushort4*)dst = o4a;
        *(ushort4*)(dst + 4) = o4b;
    }
}

// Fused GEMM1+LN+GEMM2+LN+residual (r2-proven version, unchanged).
// grid 256 (1 block/CU), 512 thr / 8 waves, 128 rows per block.
__global__ __launch_bounds__(512, 1) void k_fused(
    const float* __restrict__ x1, const unsigned short* __restrict__ wt1,
    const unsigned short* __restrict__ w2t, const unsigned short* __restrict__ vec,
    float* __restrict__ out) {
    extern __shared__ __align__(16) char pool[];
    unsigned short* n1s = (unsigned short*)pool;          // [128][264]
    char* Breg = pool + 67584;

    const int t = threadIdx.x;
    const int lane = t & 63, w = t >> 6;
    const int l15 = lane & 15, quad = lane >> 4;
    const int rb = blockIdx.x;
    const int row0 = rb << 7;
    const char* wt1c = (const char*)wt1;
    const char* wbase = (const char*)w2t + (size_t)(rb >> 5) * 262144;

    const float* xrow = x1 + (size_t)(row0 + (w << 4) + l15) * 512 + quad * 8;

    f32x4 acc[16];
#pragma unroll
    for (int i = 0; i < 16; i++) acc[i] = (f32x4){0.f, 0.f, 0.f, 0.f};

#pragma unroll
    for (int i = 0; i < 2; i++)
        gl16(wt1c + ((w * 2 + i) << 10) + lane * 16,
             Breg + ((w * 2 + i) << 10) + lane * 16);
    float4 fa[2][2];
    fa[0][0] = *(const float4*)xrow;
    fa[0][1] = *(const float4*)(xrow + 4);

    // ---- Phase 1: K=512, 16 steps ----
#pragma unroll
    for (int s = 0; s < 16; ++s) {
        const int cur = s & 1;
        if (s < 15) {
            const float* xn = xrow + (s + 1) * 32;
            fa[cur ^ 1][0] = *(const float4*)xn;
            fa[cur ^ 1][1] = *(const float4*)(xn + 4);
#pragma unroll
            for (int i = 0; i < 2; i++)
                gl16(wt1c + (size_t)(s + 1) * 16384 + ((w * 2 + i) << 10) + lane * 16,
                     Breg + (cur ^ 1) * 16384 + ((w * 2 + i) << 10) + lane * 16);
        }
        bf16x8 af;
        af[0] = (__bf16)fa[cur][0].x; af[1] = (__bf16)fa[cur][0].y;
        af[2] = (__bf16)fa[cur][0].z; af[3] = (__bf16)fa[cur][0].w;
        af[4] = (__bf16)fa[cur][1].x; af[5] = (__bf16)fa[cur][1].y;
        af[6] = (__bf16)fa[cur][1].z; af[7] = (__bf16)fa[cur][1].w;
        if (s < 15) { WAITVM(4); } else { WAITVM(0); }
        __builtin_amdgcn_s_barrier();
        const char* Bc = Breg + cur * 16384 + quad * 4096 + l15 * 16;
#pragma unroll
        for (int cb = 0; cb < 16; cb++) {
            bf16x8 bf = *(const bf16x8*)(Bc + cb * 256);
            acc[cb] = __builtin_amdgcn_mfma_f32_16x16x32_bf16(af, bf, acc[cb], 0, 0, 0);
        }
        WAITLGKM0;
        __builtin_amdgcn_s_barrier();
    }

    // ---- Phase 1 epilogue: bias + LN(256) -> n1s ----
    float bc_[16], gg_[16], bb_[16];
#pragma unroll
    for (int cb = 0; cb < 16; cb++) {
        int col = (cb << 4) + l15;
        bc_[cb] = b2f(vec[col]);
        gg_[cb] = b2f(vec[256 + col]);
        bb_[cb] = b2f(vec[512 + col]);
    }
#pragma unroll
    for (int i = 0; i < 4; i++)
        gl16(wbase + ((w * 4 + i) << 10) + lane * 16,
             Breg + 32768 + ((w * 4 + i) << 10) + lane * 16);

#pragma unroll
    for (int cb = 0; cb < 16; cb++) {
#pragma unroll
        for (int r = 0; r < 4; r++) acc[cb][r] += bc_[cb];
    }
    float mean_[4], rstd_[4];
#pragma unroll
    for (int r = 0; r < 4; r++) {
        float s = 0.f, q = 0.f;
#pragma unroll
        for (int cb = 0; cb < 16; cb++) { float v = acc[cb][r]; s += v; q += v * v; }
#pragma unroll
        for (int msk = 1; msk < 16; msk <<= 1) {
            s += __shfl_xor(s, msk, 64);
            q += __shfl_xor(q, msk, 64);
        }
        float mn = s * (1.0f / 256.0f);
        mean_[r] = mn;
        rstd_[r] = rsqrtf(q * (1.0f / 256.0f) - mn * mn + EPS);
    }
#pragma unroll
    for (int cb = 0; cb < 16; cb++) {
        int col = (cb << 4) + l15;
#pragma unroll
        for (int r = 0; r < 4; r++) {
            int rr = (w << 4) + (quad << 2) + r;
            n1s[rr * 264 + col] =
                f2b((acc[cb][r] - mean_[r]) * rstd_[r] * gg_[cb] + bb_[cb]);
        }
    }
    WAITLGKM0;
    __builtin_amdgcn_s_barrier();

    // ---- Phase 2: K=256, 8 steps ----
    f32x4 acc2[32];
#pragma unroll
    for (int i = 0; i < 32; i++) acc2[i] = (f32x4){0.f, 0.f, 0.f, 0.f};
    const unsigned short* an1 = n1s + ((w << 4) + l15) * 264 + quad * 8;

#pragma unroll
    for (int s = 0; s < 8; ++s) {
        const char* bufc = Breg + ((s & 1) ? 0 : 32768);
        if (s < 7) {
            char* bufn = Breg + (((s + 1) & 1) ? 0 : 32768);
#pragma unroll
            for (int i = 0; i < 4; i++)
                gl16(wbase + (size_t)(s + 1) * 32768 + ((w * 4 + i) << 10) + lane * 16,
                     bufn + ((w * 4 + i) << 10) + lane * 16);
        }
        bf16x8 a2 = *(const bf16x8*)(an1 + s * 32);
        if (s < 7) { WAITVM(4); } else { WAITVM(0); }
        __builtin_amdgcn_s_barrier();
        const char* Bc = bufc + quad * 8192 + l15 * 16;
#pragma unroll
        for (int cb = 0; cb < 32; cb++) {
            bf16x8 bf = *(const bf16x8*)(Bc + cb * 256);
            acc2[cb] = __builtin_amdgcn_mfma_f32_16x16x32_bf16(a2, bf, acc2[cb], 0, 0, 0);
        }
        WAITLGKM0;
        __builtin_amdgcn_s_barrier();
    }

    // ---- Phase 2 epilogue: + rb, LN(512), residual, store ----
#pragma unroll
    for (int cb = 0; cb < 32; cb++) {
        float bc = b2f(vec[768 + (cb << 4) + l15]);
#pragma unroll
        for (int r = 0; r < 4; r++) acc2[cb][r] += bc;
    }
    float mean2[4], rstd2[4];
#pragma unroll
    for (int r = 0; r < 4; r++) {
        float s = 0.f, q = 0.f;
#pragma unroll
        for (int cb = 0; cb < 32; cb++) { float v = acc2[cb][r]; s += v; q += v * v; }
#pragma unroll
        for (int msk = 1; msk < 16; msk <<= 1) {
            s += __shfl_xor(s, msk, 64);
            q += __shfl_xor(q, msk, 64);
        }
        float mn = s * (1.0f / 512.0f);
        mean2[r] = mn;
        rstd2[r] = rsqrtf(q * (1.0f / 512.0f) - mn * mn + EPS);
    }
    float* rep = (float*)pool;   // [64][516] f32 per row-half (aliases n1s+Breg)
    const int hfw = w >> 2;
#pragma unroll
    for (int hv = 0; hv < 2; ++hv) {
        if (hv) __builtin_amdgcn_s_barrier();
        if (hfw == hv) {
#pragma unroll
            for (int cb = 0; cb < 32; cb++) {
                int col = (cb << 4) + l15;
                float gg = b2f(vec[1280 + col]), bbv = b2f(vec[1792 + col]);
                int rl = ((w & 3) << 4) + (quad << 2);
#pragma unroll
                for (int r = 0; r < 4; r++)
                    rep[(rl + r) * 516 + col] =
                        (acc2[cb][r] - mean2[r]) * rstd2[r] * gg + bbv;
            }
        }
        WAITLGKM0;
        __builtin_amdgcn_s_barrier();
        int rr = t >> 4, c0 = (t & 15) << 2;
#pragma unroll
        for (int j = 0; j < 8; j++) {
            int col = c0 + (j << 6);
            float4 v0 = *(const float4*)(rep + rr * 516 + col);
            float4 v1 = *(const float4*)(rep + (rr + 32) * 516 + col);
            size_t g0 = (size_t)(row0 + (hv << 6) + rr) * 512 + col;
            size_t g1 = g0 + (size_t)32 * 512;
            float4 xa = *(const float4*)(x1 + g0);
            float4 xb = *(const float4*)(x1 + g1);
            v0.x += xa.x; v0.y += xa.y; v0.z += xa.z; v0.w += xa.w;
            v1.x += xb.x; v1.y += xb.y; v1.z += xb.z; v1.w += xb.w;
            *(float4*)(out + g0) = v0;
            *(float4*)(out + g1) = v1;
        }
        WAITLGKM0;
        __builtin_amdgcn_s_barrier();
    }
}

extern "C" void kernel_launch(void* const* d_in, const int* in_sizes, int n_in,
                              void* d_out, int out_size, void* d_ws, size_t ws_size,
                              hipStream_t stream) {
    const float* x1 = (const float*)d_in[0];
    const float* x2 = (const float*)d_in[1];
    const float* lw = (const float*)d_in[2];
    const float* lb = (const float*)d_in[3];
    const float* g1 = (const float*)d_in[4];
    const float* b1 = (const float*)d_in[5];
    const float* rw = (const float*)d_in[6];
    const float* rb = (const float*)d_in[7];
    const float* ga = (const float*)d_in[8];
    const float* ba = (const float*)d_in[9];
    float* out = (float*)d_out;

    char* ws = (char*)d_ws;
    float*          ctxr  = (float*)(ws);                       // 256 KB
    float2*         stats = (float2*)(ws + 262144);             // 256 KB
    unsigned short* wt1   = (unsigned short*)(ws + 524288);     // 256 KB
    unsigned short* rwb   = (unsigned short*)(ws + 786432);     // 256 KB
    unsigned short* vec   = (unsigned short*)(ws + 1048576);    // 4.5 KB
    unsigned short* w2t   = (unsigned short*)(ws + 1064960);    // 2 MB

    static bool attr_set = false;
    if (!attr_set) {
        hipFuncSetAttribute((const void*)k_fused,
                            hipFuncAttributeMaxDynamicSharedMemorySize, 133120);
        attr_set = true;
    }

    void* kargs[] = {
        (void*)&x2, (void*)&lw, (void*)&rw, (void*)&lb, (void*)&g1, (void*)&b1,
        (void*)&rb, (void*)&ga, (void*)&ba, (void*)&wt1, (void*)&rwb, (void*)&vec,
        (void*)&stats, (void*)&ctxr, (void*)&w2t
    };
    hipLaunchCooperativeKernel((void*)k_attn, dim3(512), dim3(256), kargs, 0, stream);
    k_fused<<<dim3(256), dim3(512), 133120, stream>>>(x1, wt1, w2t, vec, out);
}